// Round 1
// baseline (1356.707 us; speedup 1.0000x reference)
//
#include <hip/hip_runtime.h>
#include <hip/hip_bf16.h>

#define HID 1024
#define INTER_ 4096
#define NE 8
#define NTOK 8192
#define NPAIR (NTOK * 2)

using f32x4 = __attribute__((ext_vector_type(4))) float;
using bf16x8 = __attribute__((ext_vector_type(8))) __bf16;
using ushort8v = __attribute__((ext_vector_type(8))) unsigned short;

__device__ __forceinline__ unsigned short f2b(float f) {
  unsigned int u = __float_as_uint(f);
  u += 0x7fffu + ((u >> 16) & 1u);
  return (unsigned short)(u >> 16);
}

// ---------------- gating: one wave per token, fp32 ----------------
__global__ __launch_bounds__(256) void gate_kernel(
    const float* __restrict__ x, const float* __restrict__ gw,
    int* __restrict__ topi, float* __restrict__ topw, int* __restrict__ counts)
{
  int gwave = (blockIdx.x * 256 + threadIdx.x) >> 6;
  int lane = threadIdx.x & 63;
  if (gwave >= NTOK) return;
  const float* xr = x + (size_t)gwave * HID;
  float acc[NE];
#pragma unroll
  for (int e = 0; e < NE; ++e) acc[e] = 0.f;
#pragma unroll
  for (int q = 0; q < 4; ++q) {
    float4 v = *reinterpret_cast<const float4*>(xr + q * 256 + lane * 4);
#pragma unroll
    for (int e = 0; e < NE; ++e) {
      float4 wv = *reinterpret_cast<const float4*>(gw + e * HID + q * 256 + lane * 4);
      acc[e] += v.x * wv.x + v.y * wv.y + v.z * wv.z + v.w * wv.w;
    }
  }
#pragma unroll
  for (int e = 0; e < NE; ++e) {
#pragma unroll
    for (int off = 32; off > 0; off >>= 1) acc[e] += __shfl_xor(acc[e], off);
  }
  if (lane == 0) {
    float v0 = -1e30f; int i0 = 0;
#pragma unroll
    for (int e = 0; e < NE; ++e) if (acc[e] > v0) { v0 = acc[e]; i0 = e; }
    float v1 = -1e30f; int i1 = 0;
#pragma unroll
    for (int e = 0; e < NE; ++e) if (e != i0 && acc[e] > v1) { v1 = acc[e]; i1 = e; }
    float e1 = __expf(v1 - v0);
    float s = 1.f + e1;
    topi[gwave * 2] = i0; topi[gwave * 2 + 1] = i1;
    topw[gwave * 2] = 1.f / s; topw[gwave * 2 + 1] = e1 / s;
    atomicAdd(&counts[i0], 1);
    atomicAdd(&counts[i1], 1);
  }
}

__global__ void scan_kernel(const int* __restrict__ counts, int* __restrict__ offs,
                            int* __restrict__ cursors)
{
  if (threadIdx.x == 0 && blockIdx.x == 0) {
    int o = 0;
    for (int e = 0; e < NE; ++e) { offs[e] = o; cursors[e] = o; o += counts[e]; }
    offs[NE] = o;
  }
}

__global__ __launch_bounds__(256) void scatter_kernel(
    const int* __restrict__ topi, const float* __restrict__ topw,
    int* __restrict__ cursors, int* __restrict__ toklist, float* __restrict__ wlist)
{
  int t = blockIdx.x * 256 + threadIdx.x;
  if (t >= NTOK) return;
#pragma unroll
  for (int k = 0; k < 2; ++k) {
    int e = topi[t * 2 + k];
    int p = atomicAdd(&cursors[e], 1);
    toklist[p] = t;
    wlist[p] = topw[t * 2 + k];
  }
}

// ---------------- GEMM1: h = gelu(x @ W1[e]^T + b1[e]) -> bf16 ----------------
__global__ __launch_bounds__(256) void gemm1_kernel(
    const float* __restrict__ x, const float* __restrict__ W1, const float* __restrict__ b1,
    const int* __restrict__ toklist, const int* __restrict__ offs, const int* __restrict__ counts,
    unsigned short* __restrict__ hb)
{
  const int e = blockIdx.z;
  const int cnt = counts[e];
  const int m0 = blockIdx.x * 128;
  if (m0 >= cnt) return;
  const int n0 = blockIdx.y * 128;
  const int base = offs[e];

  __shared__ __align__(16) unsigned short As[128 * 32];
  __shared__ __align__(16) unsigned short Bs[128 * 32];

  const int tid = threadIdx.x;
  const int lane = tid & 63;
  const int w = tid >> 6;
  const int wr = w >> 1, wc = w & 1;

  const float* gA[2]; const float* gB[2];
  unsigned short* lA[2]; unsigned short* lB[2];
#pragma unroll
  for (int q = 0; q < 2; ++q) {
    int slot = q * 256 + tid;
    int row = slot >> 2, ks = slot & 3;
    int mrow = m0 + row; if (mrow > cnt - 1) mrow = cnt - 1;
    int tk = toklist[base + mrow];
    gA[q] = x + (size_t)tk * HID + ks * 8;
    gB[q] = W1 + ((size_t)e * INTER_ + n0 + row) * HID + ks * 8;
    int ksz = ks ^ ((row >> 1) & 3);          // bank swizzle (write side)
    lA[q] = As + row * 32 + ksz * 8;
    lB[q] = Bs + row * 32 + ksz * 8;
  }
  int ra[4], rb[4];
#pragma unroll
  for (int i = 0; i < 4; ++i) {
    int rowA = wr * 64 + i * 16 + (lane & 15);
    int rowB = wc * 64 + i * 16 + (lane & 15);
    int q = lane >> 4;
    ra[i] = rowA * 32 + (q ^ ((rowA >> 1) & 3)) * 8;  // swizzle (read side)
    rb[i] = rowB * 32 + (q ^ ((rowB >> 1) & 3)) * 8;
  }

  f32x4 acc[4][4];
#pragma unroll
  for (int i = 0; i < 4; ++i)
#pragma unroll
    for (int j = 0; j < 4; ++j) acc[i][j] = (f32x4){0.f, 0.f, 0.f, 0.f};

  for (int k0 = 0; k0 < HID; k0 += 32) {
    __syncthreads();
#pragma unroll
    for (int q = 0; q < 2; ++q) {
      float4 a0 = *reinterpret_cast<const float4*>(gA[q] + k0);
      float4 a1 = *reinterpret_cast<const float4*>(gA[q] + k0 + 4);
      float4 b0 = *reinterpret_cast<const float4*>(gB[q] + k0);
      float4 b1v = *reinterpret_cast<const float4*>(gB[q] + k0 + 4);
      ushort8v ua, ub;
      ua[0] = f2b(a0.x); ua[1] = f2b(a0.y); ua[2] = f2b(a0.z); ua[3] = f2b(a0.w);
      ua[4] = f2b(a1.x); ua[5] = f2b(a1.y); ua[6] = f2b(a1.z); ua[7] = f2b(a1.w);
      ub[0] = f2b(b0.x); ub[1] = f2b(b0.y); ub[2] = f2b(b0.z); ub[3] = f2b(b0.w);
      ub[4] = f2b(b1v.x); ub[5] = f2b(b1v.y); ub[6] = f2b(b1v.z); ub[7] = f2b(b1v.w);
      *reinterpret_cast<ushort8v*>(lA[q]) = ua;
      *reinterpret_cast<ushort8v*>(lB[q]) = ub;
    }
    __syncthreads();
    bf16x8 af[4], bfr[4];
#pragma unroll
    for (int i = 0; i < 4; ++i) af[i] = *reinterpret_cast<const bf16x8*>(&As[ra[i]]);
#pragma unroll
    for (int j = 0; j < 4; ++j) bfr[j] = *reinterpret_cast<const bf16x8*>(&Bs[rb[j]]);
#pragma unroll
    for (int i = 0; i < 4; ++i)
#pragma unroll
      for (int j = 0; j < 4; ++j)
        acc[i][j] = __builtin_amdgcn_mfma_f32_16x16x32_bf16(af[i], bfr[j], acc[i][j], 0, 0, 0);
  }

  float bias[4];
  const int colb = n0 + wc * 64 + (lane & 15);
#pragma unroll
  for (int j = 0; j < 4; ++j) bias[j] = b1[(size_t)e * INTER_ + colb + j * 16];
#pragma unroll
  for (int i = 0; i < 4; ++i) {
#pragma unroll
    for (int r = 0; r < 4; ++r) {
      int m = m0 + wr * 64 + i * 16 + (lane >> 4) * 4 + r;
      if (m < cnt) {
        size_t ro = (size_t)(base + m) * INTER_;
#pragma unroll
        for (int j = 0; j < 4; ++j) {
          float v = acc[i][j][r] + bias[j];
          float g = 0.5f * v * (1.f + erff(v * 0.70710678118654752f));  // exact gelu
          hb[ro + colb + j * 16] = f2b(g);
        }
      }
    }
  }
}

// ---------------- GEMM2: out += w * (h @ W2[e]^T + b2[e]) ----------------
__global__ __launch_bounds__(256) void gemm2_kernel(
    const unsigned short* __restrict__ hb, const float* __restrict__ W2, const float* __restrict__ b2,
    const int* __restrict__ toklist, const float* __restrict__ wlist,
    const int* __restrict__ offs, const int* __restrict__ counts,
    float* __restrict__ out)
{
  const int e = blockIdx.z;
  const int cnt = counts[e];
  const int m0 = blockIdx.x * 128;
  if (m0 >= cnt) return;
  const int n0 = blockIdx.y * 128;
  const int base = offs[e];

  __shared__ __align__(16) unsigned short As[128 * 32];
  __shared__ __align__(16) unsigned short Bs[128 * 32];

  const int tid = threadIdx.x;
  const int lane = tid & 63;
  const int w = tid >> 6;
  const int wr = w >> 1, wc = w & 1;

  const unsigned short* gA[2]; const float* gB[2];
  unsigned short* lA[2]; unsigned short* lB[2];
#pragma unroll
  for (int q = 0; q < 2; ++q) {
    int slot = q * 256 + tid;
    int row = slot >> 2, ks = slot & 3;
    int mrow = m0 + row; if (mrow > cnt - 1) mrow = cnt - 1;
    gA[q] = hb + (size_t)(base + mrow) * INTER_ + ks * 8;
    gB[q] = W2 + ((size_t)e * HID + n0 + row) * INTER_ + ks * 8;
    int ksz = ks ^ ((row >> 1) & 3);
    lA[q] = As + row * 32 + ksz * 8;
    lB[q] = Bs + row * 32 + ksz * 8;
  }
  int ra[4], rb[4];
#pragma unroll
  for (int i = 0; i < 4; ++i) {
    int rowA = wr * 64 + i * 16 + (lane & 15);
    int rowB = wc * 64 + i * 16 + (lane & 15);
    int q = lane >> 4;
    ra[i] = rowA * 32 + (q ^ ((rowA >> 1) & 3)) * 8;
    rb[i] = rowB * 32 + (q ^ ((rowB >> 1) & 3)) * 8;
  }

  f32x4 acc[4][4];
#pragma unroll
  for (int i = 0; i < 4; ++i)
#pragma unroll
    for (int j = 0; j < 4; ++j) acc[i][j] = (f32x4){0.f, 0.f, 0.f, 0.f};

  for (int k0 = 0; k0 < INTER_; k0 += 32) {
    __syncthreads();
#pragma unroll
    for (int q = 0; q < 2; ++q) {
      ushort8v ua = *reinterpret_cast<const ushort8v*>(gA[q] + k0);
      float4 b0 = *reinterpret_cast<const float4*>(gB[q] + k0);
      float4 b1v = *reinterpret_cast<const float4*>(gB[q] + k0 + 4);
      ushort8v ub;
      ub[0] = f2b(b0.x); ub[1] = f2b(b0.y); ub[2] = f2b(b0.z); ub[3] = f2b(b0.w);
      ub[4] = f2b(b1v.x); ub[5] = f2b(b1v.y); ub[6] = f2b(b1v.z); ub[7] = f2b(b1v.w);
      *reinterpret_cast<ushort8v*>(lA[q]) = ua;
      *reinterpret_cast<ushort8v*>(lB[q]) = ub;
    }
    __syncthreads();
    bf16x8 af[4], bfr[4];
#pragma unroll
    for (int i = 0; i < 4; ++i) af[i] = *reinterpret_cast<const bf16x8*>(&As[ra[i]]);
#pragma unroll
    for (int j = 0; j < 4; ++j) bfr[j] = *reinterpret_cast<const bf16x8*>(&Bs[rb[j]]);
#pragma unroll
    for (int i = 0; i < 4; ++i)
#pragma unroll
      for (int j = 0; j < 4; ++j)
        acc[i][j] = __builtin_amdgcn_mfma_f32_16x16x32_bf16(af[i], bfr[j], acc[i][j], 0, 0, 0);
  }

  float bias[4];
  const int colb = n0 + wc * 64 + (lane & 15);
#pragma unroll
  for (int j = 0; j < 4; ++j) bias[j] = b2[(size_t)e * HID + colb + j * 16];
#pragma unroll
  for (int i = 0; i < 4; ++i) {
#pragma unroll
    for (int r = 0; r < 4; ++r) {
      int m = m0 + wr * 64 + i * 16 + (lane >> 4) * 4 + r;
      if (m < cnt) {
        int tk = toklist[base + m];
        float wt = wlist[base + m];
        size_t oo = (size_t)tk * HID + colb;
#pragma unroll
        for (int j = 0; j < 4; ++j)
          atomicAdd(&out[oo + j * 16], wt * (acc[i][j][r] + bias[j]));
      }
    }
  }
}

extern "C" void kernel_launch(void* const* d_in, const int* in_sizes, int n_in,
                              void* d_out, int out_size, void* d_ws, size_t ws_size,
                              hipStream_t stream) {
  const float* x  = (const float*)d_in[0];
  const float* gw = (const float*)d_in[1];
  const float* W1 = (const float*)d_in[2];
  const float* b1 = (const float*)d_in[3];
  const float* W2 = (const float*)d_in[4];
  const float* b2 = (const float*)d_in[5];
  float* out = (float*)d_out;

  char* ws = (char*)d_ws;
  size_t off = 0;
  auto alloc = [&](size_t bytes) -> void* {
    void* p = ws + off;
    off += (bytes + 255) & ~(size_t)255;
    return p;
  };
  unsigned short* hb = (unsigned short*)alloc((size_t)NPAIR * INTER_ * 2);  // 134.2 MB
  int*   toklist = (int*)alloc(NPAIR * 4);
  float* wlist   = (float*)alloc(NPAIR * 4);
  int*   topi    = (int*)alloc(NTOK * 2 * 4);
  float* topw    = (float*)alloc(NTOK * 2 * 4);
  int*   counts  = (int*)alloc(64);
  int*   offs    = (int*)alloc(64);
  int*   cursors = (int*)alloc(64);

  hipMemsetAsync(out, 0, (size_t)out_size * sizeof(float), stream);
  hipMemsetAsync(counts, 0, 64, stream);

  gate_kernel<<<NTOK / 4, 256, 0, stream>>>(x, gw, topi, topw, counts);
  scan_kernel<<<1, 1, 0, stream>>>(counts, offs, cursors);
  scatter_kernel<<<(NTOK + 255) / 256, 256, 0, stream>>>(topi, topw, cursors, toklist, wlist);
  gemm1_kernel<<<dim3(64, 32, NE), 256, 0, stream>>>(x, W1, b1, toklist, offs, counts, hb);
  gemm2_kernel<<<dim3(64, 8, NE), 256, 0, stream>>>(hb, W2, b2, toklist, wlist, offs, counts, out);
}

// Round 2
// 1205.570 us; speedup vs baseline: 1.1254x; 1.1254x over previous
//
#include <hip/hip_runtime.h>
#include <hip/hip_bf16.h>
#include <stdint.h>

#define HID 1024
#define INTER_ 4096
#define NE 8
#define NTOK 8192
#define NPAIR (NTOK * 2)

using f32x4 = __attribute__((ext_vector_type(4))) float;
using bf16x8 = __attribute__((ext_vector_type(8))) __bf16;
using ushort8v = __attribute__((ext_vector_type(8))) unsigned short;

__device__ __forceinline__ unsigned short f2b(float f) {
  unsigned int u = __float_as_uint(f);
  u += 0x7fffu + ((u >> 16) & 1u);
  return (unsigned short)(u >> 16);
}

// global -> LDS direct copy, 16B per lane. Linear LDS dest (wave-uniform base +
// lane*16), per-lane global source (gather + swizzle live on the source side).
#define GLD_LDS(gp, lp)                                                        \
  __builtin_amdgcn_global_load_lds(                                            \
      (const __attribute__((address_space(1))) unsigned int*)(const void*)(gp),\
      (__attribute__((address_space(3))) unsigned int*)(void*)(lp), 16, 0, 0)

// ---------------- fp32 -> bf16 streaming convert ----------------
__global__ __launch_bounds__(256) void cvt_kernel(const float* __restrict__ src,
                                                  unsigned short* __restrict__ dst,
                                                  int n8) {
  int stride = gridDim.x * 256;
  for (int i = blockIdx.x * 256 + threadIdx.x; i < n8; i += stride) {
    const float4* s = reinterpret_cast<const float4*>(src) + (size_t)i * 2;
    float4 a = s[0], b = s[1];
    ushort8v u;
    u[0] = f2b(a.x); u[1] = f2b(a.y); u[2] = f2b(a.z); u[3] = f2b(a.w);
    u[4] = f2b(b.x); u[5] = f2b(b.y); u[6] = f2b(b.z); u[7] = f2b(b.w);
    reinterpret_cast<ushort8v*>(dst)[i] = u;
  }
}

// ---------------- gating: one wave per token, fp32 ----------------
__global__ __launch_bounds__(256) void gate_kernel(
    const float* __restrict__ x, const float* __restrict__ gw,
    int* __restrict__ topi, float* __restrict__ topw, int* __restrict__ counts)
{
  int gwave = (blockIdx.x * 256 + threadIdx.x) >> 6;
  int lane = threadIdx.x & 63;
  if (gwave >= NTOK) return;
  const float* xr = x + (size_t)gwave * HID;
  float acc[NE];
#pragma unroll
  for (int e = 0; e < NE; ++e) acc[e] = 0.f;
#pragma unroll
  for (int q = 0; q < 4; ++q) {
    float4 v = *reinterpret_cast<const float4*>(xr + q * 256 + lane * 4);
#pragma unroll
    for (int e = 0; e < NE; ++e) {
      float4 wv = *reinterpret_cast<const float4*>(gw + e * HID + q * 256 + lane * 4);
      acc[e] += v.x * wv.x + v.y * wv.y + v.z * wv.z + v.w * wv.w;
    }
  }
#pragma unroll
  for (int e = 0; e < NE; ++e) {
#pragma unroll
    for (int off = 32; off > 0; off >>= 1) acc[e] += __shfl_xor(acc[e], off);
  }
  if (lane == 0) {
    float v0 = -1e30f; int i0 = 0;
#pragma unroll
    for (int e = 0; e < NE; ++e) if (acc[e] > v0) { v0 = acc[e]; i0 = e; }
    float v1 = -1e30f; int i1 = 0;
#pragma unroll
    for (int e = 0; e < NE; ++e) if (e != i0 && acc[e] > v1) { v1 = acc[e]; i1 = e; }
    float e1 = __expf(v1 - v0);
    float s = 1.f + e1;
    topi[gwave * 2] = i0; topi[gwave * 2 + 1] = i1;
    topw[gwave * 2] = 1.f / s; topw[gwave * 2 + 1] = e1 / s;
    atomicAdd(&counts[i0], 1);
    atomicAdd(&counts[i1], 1);
  }
}

__global__ void scan_kernel(const int* __restrict__ counts, int* __restrict__ offs,
                            int* __restrict__ cursors)
{
  if (threadIdx.x == 0 && blockIdx.x == 0) {
    int o = 0;
    for (int e = 0; e < NE; ++e) { offs[e] = o; cursors[e] = o; o += counts[e]; }
    offs[NE] = o;
  }
}

__global__ __launch_bounds__(256) void scatter_kernel(
    const int* __restrict__ topi, const float* __restrict__ topw,
    int* __restrict__ cursors, int* __restrict__ toklist, float* __restrict__ wlist)
{
  int t = blockIdx.x * 256 + threadIdx.x;
  if (t >= NTOK) return;
#pragma unroll
  for (int k = 0; k < 2; ++k) {
    int e = topi[t * 2 + k];
    int p = atomicAdd(&cursors[e], 1);
    toklist[p] = t;
    wlist[p] = topw[t * 2 + k];
  }
}

// ============ GEMM1: h = gelu(x @ W1[e]^T + b1[e]) -> bf16 ============
// 128x128 tile, BK=64, 4 waves (2x2), global_load_lds width=16,
// XOR col-group swizzle (linear LDS dest + inverse-swz source + swz read).
__global__ __launch_bounds__(256) void gemm1_kernel(
    const unsigned short* __restrict__ xb, const unsigned short* __restrict__ w1b,
    const float* __restrict__ b1,
    const int* __restrict__ toklist, const int* __restrict__ offs,
    const int* __restrict__ counts, unsigned short* __restrict__ hb)
{
  const int e = blockIdx.z;
  const int cnt = counts[e];
  const int m0 = blockIdx.x * 128;
  if (m0 >= cnt) return;
  const int n0 = blockIdx.y * 128;
  const int base = offs[e];

  __shared__ __align__(16) unsigned short As[128 * 64];
  __shared__ __align__(16) unsigned short Bs[128 * 64];

  const int tid = threadIdx.x;
  const int lane = tid & 63;
  const int w = tid >> 6;
  const int wr = w >> 1, wc = w & 1;

  // source col-group swizzle: LDS slot (row, s) holds global col-group s^(row&7)
  const int col8 = (tid & 7) ^ ((tid >> 3) & 7);
  const unsigned short* gA[4];
  const unsigned short* gB[4];
#pragma unroll
  for (int n = 0; n < 4; ++n) {
    int row = n * 32 + (tid >> 3);
    int mrow = m0 + row; if (mrow >= cnt) mrow = cnt - 1;
    int tk = toklist[base + mrow];
    gA[n] = xb + (size_t)tk * HID + col8 * 8;
    gB[n] = w1b + ((size_t)e * INTER_ + n0 + row) * HID + col8 * 8;
  }

  // fragment read addresses (ushort offsets), swizzled
  int raddr[2][4], rbaddr[2][4];
#pragma unroll
  for (int kk = 0; kk < 2; ++kk)
#pragma unroll
    for (int i = 0; i < 4; ++i) {
      int cg = kk * 4 + (lane >> 4);
      int rowA = wr * 64 + i * 16 + (lane & 15);
      raddr[kk][i] = rowA * 64 + ((cg ^ (rowA & 7)) * 8);
      int rowB = wc * 64 + i * 16 + (lane & 15);
      rbaddr[kk][i] = rowB * 64 + ((cg ^ (rowB & 7)) * 8);
    }

  f32x4 acc[4][4];
#pragma unroll
  for (int i = 0; i < 4; ++i)
#pragma unroll
    for (int j = 0; j < 4; ++j) acc[i][j] = (f32x4){0.f, 0.f, 0.f, 0.f};

  for (int kt = 0; kt < HID / 64; ++kt) {
    const int kof = kt * 64;
#pragma unroll
    for (int n = 0; n < 4; ++n) {
      GLD_LDS(gA[n] + kof, As + n * 2048 + tid * 8);
      GLD_LDS(gB[n] + kof, Bs + n * 2048 + tid * 8);
    }
    __syncthreads();
#pragma unroll
    for (int kk = 0; kk < 2; ++kk) {
      bf16x8 af[4], bfr[4];
#pragma unroll
      for (int i = 0; i < 4; ++i) af[i] = *reinterpret_cast<const bf16x8*>(&As[raddr[kk][i]]);
#pragma unroll
      for (int j = 0; j < 4; ++j) bfr[j] = *reinterpret_cast<const bf16x8*>(&Bs[rbaddr[kk][j]]);
#pragma unroll
      for (int i = 0; i < 4; ++i)
#pragma unroll
        for (int j = 0; j < 4; ++j)
          acc[i][j] = __builtin_amdgcn_mfma_f32_16x16x32_bf16(af[i], bfr[j], acc[i][j], 0, 0, 0);
    }
    __syncthreads();
  }

  float bias[4];
  const int colb = n0 + wc * 64 + (lane & 15);
#pragma unroll
  for (int j = 0; j < 4; ++j) bias[j] = b1[(size_t)e * INTER_ + colb + j * 16];
#pragma unroll
  for (int i = 0; i < 4; ++i) {
    int mbase = m0 + wr * 64 + i * 16 + (lane >> 4) * 4;
#pragma unroll
    for (int r = 0; r < 4; ++r) {
      int m = mbase + r;
      if (m < cnt) {
        size_t ro = (size_t)(base + m) * INTER_;
#pragma unroll
        for (int j = 0; j < 4; ++j) {
          float v = acc[i][j][r] + bias[j];
          float g = 0.5f * v * (1.f + erff(v * 0.70710678118654752f));
          hb[ro + colb + j * 16] = f2b(g);
        }
      }
    }
  }
}

// ============ GEMM2: out += w * (h @ W2[e]^T + b2[e]) ============
__global__ __launch_bounds__(256) void gemm2_kernel(
    const unsigned short* __restrict__ hb, const unsigned short* __restrict__ w2b,
    const float* __restrict__ b2,
    const int* __restrict__ toklist, const float* __restrict__ wlist,
    const int* __restrict__ offs, const int* __restrict__ counts,
    float* __restrict__ out)
{
  const int e = blockIdx.z;
  const int cnt = counts[e];
  const int m0 = blockIdx.x * 128;
  if (m0 >= cnt) return;
  const int n0 = blockIdx.y * 128;
  const int base = offs[e];

  __shared__ __align__(16) unsigned short As[128 * 64];
  __shared__ __align__(16) unsigned short Bs[128 * 64];

  const int tid = threadIdx.x;
  const int lane = tid & 63;
  const int w = tid >> 6;
  const int wr = w >> 1, wc = w & 1;

  const int col8 = (tid & 7) ^ ((tid >> 3) & 7);
  const unsigned short* gA[4];
  const unsigned short* gB[4];
#pragma unroll
  for (int n = 0; n < 4; ++n) {
    int row = n * 32 + (tid >> 3);
    int mrow = m0 + row; if (mrow >= cnt) mrow = cnt - 1;
    gA[n] = hb + (size_t)(base + mrow) * INTER_ + col8 * 8;
    gB[n] = w2b + ((size_t)e * HID + n0 + row) * INTER_ + col8 * 8;
  }

  int raddr[2][4], rbaddr[2][4];
#pragma unroll
  for (int kk = 0; kk < 2; ++kk)
#pragma unroll
    for (int i = 0; i < 4; ++i) {
      int cg = kk * 4 + (lane >> 4);
      int rowA = wr * 64 + i * 16 + (lane & 15);
      raddr[kk][i] = rowA * 64 + ((cg ^ (rowA & 7)) * 8);
      int rowB = wc * 64 + i * 16 + (lane & 15);
      rbaddr[kk][i] = rowB * 64 + ((cg ^ (rowB & 7)) * 8);
    }

  f32x4 acc[4][4];
#pragma unroll
  for (int i = 0; i < 4; ++i)
#pragma unroll
    for (int j = 0; j < 4; ++j) acc[i][j] = (f32x4){0.f, 0.f, 0.f, 0.f};

  for (int kt = 0; kt < INTER_ / 64; ++kt) {
    const int kof = kt * 64;
#pragma unroll
    for (int n = 0; n < 4; ++n) {
      GLD_LDS(gA[n] + kof, As + n * 2048 + tid * 8);
      GLD_LDS(gB[n] + kof, Bs + n * 2048 + tid * 8);
    }
    __syncthreads();
#pragma unroll
    for (int kk = 0; kk < 2; ++kk) {
      bf16x8 af[4], bfr[4];
#pragma unroll
      for (int i = 0; i < 4; ++i) af[i] = *reinterpret_cast<const bf16x8*>(&As[raddr[kk][i]]);
#pragma unroll
      for (int j = 0; j < 4; ++j) bfr[j] = *reinterpret_cast<const bf16x8*>(&Bs[rbaddr[kk][j]]);
#pragma unroll
      for (int i = 0; i < 4; ++i)
#pragma unroll
        for (int j = 0; j < 4; ++j)
          acc[i][j] = __builtin_amdgcn_mfma_f32_16x16x32_bf16(af[i], bfr[j], acc[i][j], 0, 0, 0);
    }
    __syncthreads();
  }

  float bias[4];
  const int colb = n0 + wc * 64 + (lane & 15);
#pragma unroll
  for (int j = 0; j < 4; ++j) bias[j] = b2[(size_t)e * HID + colb + j * 16];
#pragma unroll
  for (int i = 0; i < 4; ++i) {
    int mbase = m0 + wr * 64 + i * 16 + (lane >> 4) * 4;
#pragma unroll
    for (int r = 0; r < 4; ++r) {
      int m = mbase + r;
      if (m < cnt) {
        int tk = toklist[base + m];
        float wt = wlist[base + m];
        size_t oo = (size_t)tk * HID + colb;
#pragma unroll
        for (int j = 0; j < 4; ++j)
          atomicAdd(&out[oo + j * 16], wt * (acc[i][j][r] + bias[j]));
      }
    }
  }
}

extern "C" void kernel_launch(void* const* d_in, const int* in_sizes, int n_in,
                              void* d_out, int out_size, void* d_ws, size_t ws_size,
                              hipStream_t stream) {
  const float* x  = (const float*)d_in[0];
  const float* gw = (const float*)d_in[1];
  const float* W1 = (const float*)d_in[2];
  const float* b1 = (const float*)d_in[3];
  const float* W2 = (const float*)d_in[4];
  const float* b2 = (const float*)d_in[5];
  float* out = (float*)d_out;

  char* ws = (char*)d_ws;
  size_t off = 0;
  auto alloc = [&](size_t bytes) -> void* {
    void* p = ws + off;
    off += (bytes + 255) & ~(size_t)255;
    return p;
  };
  unsigned short* hb  = (unsigned short*)alloc((size_t)NPAIR * INTER_ * 2); // 134.2 MB
  unsigned short* xb  = (unsigned short*)alloc((size_t)NTOK * HID * 2);     //  16.8 MB
  unsigned short* w1b = (unsigned short*)alloc((size_t)NE * INTER_ * HID * 2); // 67.1 MB
  unsigned short* w2b = (unsigned short*)alloc((size_t)NE * HID * INTER_ * 2); // 67.1 MB
  int*   toklist = (int*)alloc(NPAIR * 4);
  float* wlist   = (float*)alloc(NPAIR * 4);
  int*   topi    = (int*)alloc(NTOK * 2 * 4);
  float* topw    = (float*)alloc(NTOK * 2 * 4);
  int*   counts  = (int*)alloc(64);
  int*   offs    = (int*)alloc(64);
  int*   cursors = (int*)alloc(64);

  hipMemsetAsync(out, 0, (size_t)out_size * sizeof(float), stream);
  hipMemsetAsync(counts, 0, 64, stream);

  gate_kernel<<<NTOK / 4, 256, 0, stream>>>(x, gw, topi, topw, counts);
  scan_kernel<<<1, 1, 0, stream>>>(counts, offs, cursors);
  scatter_kernel<<<(NTOK + 255) / 256, 256, 0, stream>>>(topi, topw, cursors, toklist, wlist);
  cvt_kernel<<<1024, 256, 0, stream>>>(x, xb, NTOK * HID / 8);
  cvt_kernel<<<2048, 256, 0, stream>>>(W1, w1b, NE * INTER_ * HID / 8);
  cvt_kernel<<<2048, 256, 0, stream>>>(W2, w2b, NE * HID * INTER_ / 8);
  gemm1_kernel<<<dim3(64, 32, NE), 256, 0, stream>>>(xb, w1b, b1, toklist, offs, counts, hb);
  gemm2_kernel<<<dim3(64, 8, NE), 256, 0, stream>>>(hb, w2b, b2, toklist, wlist, offs, counts, out);
}

// Round 3
// 880.892 us; speedup vs baseline: 1.5402x; 1.3686x over previous
//
#include <hip/hip_runtime.h>
#include <hip/hip_bf16.h>
#include <stdint.h>

#define HID 1024
#define INTER_ 4096
#define NE 8
#define NTOK 8192
#define NPAIR (NTOK * 2)
#define MAXTILE 136   // sum ceil(cnt_e/128) <= 16384/128 + 8

using f32x4 = __attribute__((ext_vector_type(4))) float;
using bf16x8 = __attribute__((ext_vector_type(8))) __bf16;
using ushort8v = __attribute__((ext_vector_type(8))) unsigned short;

__device__ __forceinline__ unsigned short f2b(float f) {
  unsigned int u = __float_as_uint(f);
  u += 0x7fffu + ((u >> 16) & 1u);
  return (unsigned short)(u >> 16);
}

#define GLD_LDS(gp, lp)                                                        \
  __builtin_amdgcn_global_load_lds(                                            \
      (const __attribute__((address_space(1))) unsigned int*)(const void*)(gp),\
      (__attribute__((address_space(3))) unsigned int*)(void*)(lp), 16, 0, 0)

// ---------------- fp32 -> bf16 streaming convert ----------------
__global__ __launch_bounds__(256) void cvt_kernel(const float* __restrict__ src,
                                                  unsigned short* __restrict__ dst,
                                                  int n8) {
  int stride = gridDim.x * 256;
  for (int i = blockIdx.x * 256 + threadIdx.x; i < n8; i += stride) {
    const float4* s = reinterpret_cast<const float4*>(src) + (size_t)i * 2;
    float4 a = s[0], b = s[1];
    ushort8v u;
    u[0] = f2b(a.x); u[1] = f2b(a.y); u[2] = f2b(a.z); u[3] = f2b(a.w);
    u[4] = f2b(b.x); u[5] = f2b(b.y); u[6] = f2b(b.z); u[7] = f2b(b.w);
    reinterpret_cast<ushort8v*>(dst)[i] = u;
  }
}

// ---------------- gating: one wave per token, fp32 ----------------
__global__ __launch_bounds__(256) void gate_kernel(
    const float* __restrict__ x, const float* __restrict__ gw,
    int* __restrict__ topi, float* __restrict__ topw, int* __restrict__ counts)
{
  int gwave = (blockIdx.x * 256 + threadIdx.x) >> 6;
  int lane = threadIdx.x & 63;
  if (gwave >= NTOK) return;
  const float* xr = x + (size_t)gwave * HID;
  float acc[NE];
#pragma unroll
  for (int e = 0; e < NE; ++e) acc[e] = 0.f;
#pragma unroll
  for (int q = 0; q < 4; ++q) {
    float4 v = *reinterpret_cast<const float4*>(xr + q * 256 + lane * 4);
#pragma unroll
    for (int e = 0; e < NE; ++e) {
      float4 wv = *reinterpret_cast<const float4*>(gw + e * HID + q * 256 + lane * 4);
      acc[e] += v.x * wv.x + v.y * wv.y + v.z * wv.z + v.w * wv.w;
    }
  }
#pragma unroll
  for (int e = 0; e < NE; ++e) {
#pragma unroll
    for (int off = 32; off > 0; off >>= 1) acc[e] += __shfl_xor(acc[e], off);
  }
  if (lane == 0) {
    float v0 = -1e30f; int i0 = 0;
#pragma unroll
    for (int e = 0; e < NE; ++e) if (acc[e] > v0) { v0 = acc[e]; i0 = e; }
    float v1 = -1e30f; int i1 = 0;
#pragma unroll
    for (int e = 0; e < NE; ++e) if (e != i0 && acc[e] > v1) { v1 = acc[e]; i1 = e; }
    float e1 = __expf(v1 - v0);
    float s = 1.f + e1;
    topi[gwave * 2] = i0; topi[gwave * 2 + 1] = i1;
    topw[gwave * 2] = 1.f / s; topw[gwave * 2 + 1] = e1 / s;
    atomicAdd(&counts[i0], 1);
    atomicAdd(&counts[i1], 1);
  }
}

// prefix scan + dense tile table (tile -> expert, row-offset)
__global__ void scan_kernel(const int* __restrict__ counts, int* __restrict__ offs,
                            int* __restrict__ cursors, int* __restrict__ tile_e,
                            int* __restrict__ tile_m, int* __restrict__ ntile)
{
  if (threadIdx.x == 0 && blockIdx.x == 0) {
    int o = 0, t = 0;
    for (int e = 0; e < NE; ++e) {
      offs[e] = o; cursors[e] = o;
      int c = counts[e];
      for (int m = 0; m < c; m += 128) { tile_e[t] = e; tile_m[t] = m; ++t; }
      o += c;
    }
    offs[NE] = o;
    *ntile = t;
  }
}

__global__ __launch_bounds__(256) void scatter_kernel(
    const int* __restrict__ topi, const float* __restrict__ topw,
    int* __restrict__ cursors, int* __restrict__ toklist, float* __restrict__ wlist)
{
  int t = blockIdx.x * 256 + threadIdx.x;
  if (t >= NTOK) return;
#pragma unroll
  for (int k = 0; k < 2; ++k) {
    int e = topi[t * 2 + k];
    int p = atomicAdd(&cursors[e], 1);
    toklist[p] = t;
    wlist[p] = topw[t * 2 + k];
  }
}

// ============ GEMM1: h = gelu(x @ W1[e]^T + b1[e]) -> bf16 ============
__global__ __launch_bounds__(256) void gemm1_kernel(
    const unsigned short* __restrict__ xb, const unsigned short* __restrict__ w1b,
    const float* __restrict__ b1,
    const int* __restrict__ toklist, const int* __restrict__ offs,
    const int* __restrict__ counts,
    const int* __restrict__ tile_e, const int* __restrict__ tile_m,
    const int* __restrict__ ntile,
    unsigned short* __restrict__ hb)
{
  const int t = blockIdx.x;
  if (t >= *ntile) return;
  const int e = tile_e[t];
  const int m0 = tile_m[t];
  const int cnt = counts[e];
  const int n0 = blockIdx.y * 128;
  const int base = offs[e];

  __shared__ __align__(16) unsigned short As[128 * 64];
  __shared__ __align__(16) unsigned short Bs[128 * 64];

  const int tid = threadIdx.x;
  const int lane = tid & 63;
  const int w = tid >> 6;
  const int wr = w >> 1, wc = w & 1;

  const int col8 = (tid & 7) ^ ((tid >> 3) & 7);
  const unsigned short* gA[4];
  const unsigned short* gB[4];
#pragma unroll
  for (int n = 0; n < 4; ++n) {
    int row = n * 32 + (tid >> 3);
    int mrow = m0 + row; if (mrow >= cnt) mrow = cnt - 1;
    int tk = toklist[base + mrow];
    gA[n] = xb + (size_t)tk * HID + col8 * 8;
    gB[n] = w1b + ((size_t)e * INTER_ + n0 + row) * HID + col8 * 8;
  }

  int raddr[2][4], rbaddr[2][4];
#pragma unroll
  for (int kk = 0; kk < 2; ++kk)
#pragma unroll
    for (int i = 0; i < 4; ++i) {
      int cg = kk * 4 + (lane >> 4);
      int rowA = wr * 64 + i * 16 + (lane & 15);
      raddr[kk][i] = rowA * 64 + ((cg ^ (rowA & 7)) * 8);
      int rowB = wc * 64 + i * 16 + (lane & 15);
      rbaddr[kk][i] = rowB * 64 + ((cg ^ (rowB & 7)) * 8);
    }

  f32x4 acc[4][4];
#pragma unroll
  for (int i = 0; i < 4; ++i)
#pragma unroll
    for (int j = 0; j < 4; ++j) acc[i][j] = (f32x4){0.f, 0.f, 0.f, 0.f};

  for (int kt = 0; kt < HID / 64; ++kt) {
    const int kof = kt * 64;
#pragma unroll
    for (int n = 0; n < 4; ++n) {
      GLD_LDS(gA[n] + kof, As + n * 2048 + tid * 8);
      GLD_LDS(gB[n] + kof, Bs + n * 2048 + tid * 8);
    }
    __syncthreads();
#pragma unroll
    for (int kk = 0; kk < 2; ++kk) {
      bf16x8 af[4], bfr[4];
#pragma unroll
      for (int i = 0; i < 4; ++i) af[i] = *reinterpret_cast<const bf16x8*>(&As[raddr[kk][i]]);
#pragma unroll
      for (int j = 0; j < 4; ++j) bfr[j] = *reinterpret_cast<const bf16x8*>(&Bs[rbaddr[kk][j]]);
#pragma unroll
      for (int i = 0; i < 4; ++i)
#pragma unroll
        for (int j = 0; j < 4; ++j)
          acc[i][j] = __builtin_amdgcn_mfma_f32_16x16x32_bf16(af[i], bfr[j], acc[i][j], 0, 0, 0);
    }
    __syncthreads();
  }

  float bias[4];
  const int colb = n0 + wc * 64 + (lane & 15);
#pragma unroll
  for (int j = 0; j < 4; ++j) bias[j] = b1[(size_t)e * INTER_ + colb + j * 16];
#pragma unroll
  for (int i = 0; i < 4; ++i) {
    int mbase = m0 + wr * 64 + i * 16 + (lane >> 4) * 4;
#pragma unroll
    for (int r = 0; r < 4; ++r) {
      int m = mbase + r;
      if (m < cnt) {
        size_t ro = (size_t)(base + m) * INTER_;
#pragma unroll
        for (int j = 0; j < 4; ++j) {
          float v = acc[i][j][r] + bias[j];
          float g = 0.5f * v * (1.f + erff(v * 0.70710678118654752f));
          hb[ro + colb + j * 16] = f2b(g);
        }
      }
    }
  }
}

// ============ GEMM2: out += w * (h @ W2[e]^T + b2[e]) ============
__global__ __launch_bounds__(256) void gemm2_kernel(
    const unsigned short* __restrict__ hb, const unsigned short* __restrict__ w2b,
    const float* __restrict__ b2,
    const int* __restrict__ toklist, const float* __restrict__ wlist,
    const int* __restrict__ offs, const int* __restrict__ counts,
    const int* __restrict__ tile_e, const int* __restrict__ tile_m,
    const int* __restrict__ ntile,
    float* __restrict__ out)
{
  const int t = blockIdx.x;
  if (t >= *ntile) return;
  const int e = tile_e[t];
  const int m0 = tile_m[t];
  const int cnt = counts[e];
  const int n0 = blockIdx.y * 128;
  const int base = offs[e];

  __shared__ __align__(16) unsigned short As[128 * 64];
  __shared__ __align__(16) unsigned short Bs[128 * 64];

  const int tid = threadIdx.x;
  const int lane = tid & 63;
  const int w = tid >> 6;
  const int wr = w >> 1, wc = w & 1;

  const int col8 = (tid & 7) ^ ((tid >> 3) & 7);
  const unsigned short* gA[4];
  const unsigned short* gB[4];
#pragma unroll
  for (int n = 0; n < 4; ++n) {
    int row = n * 32 + (tid >> 3);
    int mrow = m0 + row; if (mrow >= cnt) mrow = cnt - 1;
    gA[n] = hb + (size_t)(base + mrow) * INTER_ + col8 * 8;
    gB[n] = w2b + ((size_t)e * HID + n0 + row) * INTER_ + col8 * 8;
  }

  int raddr[2][4], rbaddr[2][4];
#pragma unroll
  for (int kk = 0; kk < 2; ++kk)
#pragma unroll
    for (int i = 0; i < 4; ++i) {
      int cg = kk * 4 + (lane >> 4);
      int rowA = wr * 64 + i * 16 + (lane & 15);
      raddr[kk][i] = rowA * 64 + ((cg ^ (rowA & 7)) * 8);
      int rowB = wc * 64 + i * 16 + (lane & 15);
      rbaddr[kk][i] = rowB * 64 + ((cg ^ (rowB & 7)) * 8);
    }

  f32x4 acc[4][4];
#pragma unroll
  for (int i = 0; i < 4; ++i)
#pragma unroll
    for (int j = 0; j < 4; ++j) acc[i][j] = (f32x4){0.f, 0.f, 0.f, 0.f};

  for (int kt = 0; kt < INTER_ / 64; ++kt) {
    const int kof = kt * 64;
#pragma unroll
    for (int n = 0; n < 4; ++n) {
      GLD_LDS(gA[n] + kof, As + n * 2048 + tid * 8);
      GLD_LDS(gB[n] + kof, Bs + n * 2048 + tid * 8);
    }
    __syncthreads();
#pragma unroll
    for (int kk = 0; kk < 2; ++kk) {
      bf16x8 af[4], bfr[4];
#pragma unroll
      for (int i = 0; i < 4; ++i) af[i] = *reinterpret_cast<const bf16x8*>(&As[raddr[kk][i]]);
#pragma unroll
      for (int j = 0; j < 4; ++j) bfr[j] = *reinterpret_cast<const bf16x8*>(&Bs[rbaddr[kk][j]]);
#pragma unroll
      for (int i = 0; i < 4; ++i)
#pragma unroll
        for (int j = 0; j < 4; ++j)
          acc[i][j] = __builtin_amdgcn_mfma_f32_16x16x32_bf16(af[i], bfr[j], acc[i][j], 0, 0, 0);
    }
    __syncthreads();
  }

  float bias[4];
  const int colb = n0 + wc * 64 + (lane & 15);
#pragma unroll
  for (int j = 0; j < 4; ++j) bias[j] = b2[(size_t)e * HID + colb + j * 16];
#pragma unroll
  for (int i = 0; i < 4; ++i) {
    int mbase = m0 + wr * 64 + i * 16 + (lane >> 4) * 4;
#pragma unroll
    for (int r = 0; r < 4; ++r) {
      int m = mbase + r;
      if (m < cnt) {
        int tk = toklist[base + m];
        float wt = wlist[base + m];
        size_t oo = (size_t)tk * HID + colb;
#pragma unroll
        for (int j = 0; j < 4; ++j)
          atomicAdd(&out[oo + j * 16], wt * (acc[i][j][r] + bias[j]));
      }
    }
  }
}

extern "C" void kernel_launch(void* const* d_in, const int* in_sizes, int n_in,
                              void* d_out, int out_size, void* d_ws, size_t ws_size,
                              hipStream_t stream) {
  const float* x  = (const float*)d_in[0];
  const float* gw = (const float*)d_in[1];
  const float* W1 = (const float*)d_in[2];
  const float* b1 = (const float*)d_in[3];
  const float* W2 = (const float*)d_in[4];
  const float* b2 = (const float*)d_in[5];
  float* out = (float*)d_out;

  char* ws = (char*)d_ws;
  size_t off = 0;
  auto alloc = [&](size_t bytes) -> void* {
    void* p = ws + off;
    off += (bytes + 255) & ~(size_t)255;
    return p;
  };
  unsigned short* hb  = (unsigned short*)alloc((size_t)NPAIR * INTER_ * 2); // 134.2 MB
  unsigned short* xb  = (unsigned short*)alloc((size_t)NTOK * HID * 2);     //  16.8 MB
  unsigned short* w1b = (unsigned short*)alloc((size_t)NE * INTER_ * HID * 2); // 67.1 MB
  unsigned short* w2b = (unsigned short*)alloc((size_t)NE * HID * INTER_ * 2); // 67.1 MB
  int*   toklist = (int*)alloc(NPAIR * 4);
  float* wlist   = (float*)alloc(NPAIR * 4);
  int*   topi    = (int*)alloc(NTOK * 2 * 4);
  float* topw    = (float*)alloc(NTOK * 2 * 4);
  int*   counts  = (int*)alloc(64);
  int*   offs    = (int*)alloc(64);
  int*   cursors = (int*)alloc(64);
  int*   tile_e  = (int*)alloc(MAXTILE * 4);
  int*   tile_m  = (int*)alloc(MAXTILE * 4);
  int*   ntile   = (int*)alloc(64);

  hipMemsetAsync(out, 0, (size_t)out_size * sizeof(float), stream);
  hipMemsetAsync(counts, 0, 64, stream);

  gate_kernel<<<NTOK / 4, 256, 0, stream>>>(x, gw, topi, topw, counts);
  scan_kernel<<<1, 1, 0, stream>>>(counts, offs, cursors, tile_e, tile_m, ntile);
  scatter_kernel<<<(NTOK + 255) / 256, 256, 0, stream>>>(topi, topw, cursors, toklist, wlist);
  cvt_kernel<<<1024, 256, 0, stream>>>(x, xb, NTOK * HID / 8);
  cvt_kernel<<<2048, 256, 0, stream>>>(W1, w1b, NE * INTER_ * HID / 8);
  cvt_kernel<<<2048, 256, 0, stream>>>(W2, w2b, NE * HID * INTER_ / 8);
  gemm1_kernel<<<dim3(MAXTILE, 32), 256, 0, stream>>>(xb, w1b, b1, toklist, offs, counts,
                                                      tile_e, tile_m, ntile, hb);
  gemm2_kernel<<<dim3(MAXTILE, 8), 256, 0, stream>>>(hb, w2b, b2, toklist, wlist, offs, counts,
                                                     tile_e, tile_m, ntile, out);
}